// Round 5
// baseline (85.147 us; speedup 1.0000x reference)
//
#include <hip/hip_runtime.h>

#define CROP   28
#define NBOX   100
#define IMG_H  512
#define IMG_W  512
#define IMG_C  32
#define BATCH  8

#define TPB    7                   // row-groups (of 4 crop rows) per box
#define TASKS_PER_IMG (NBOX * TPB) // 700
#define SORT_N 1024                // padded bitonic size
#define THREADS_PER_TASK 448       // 4 rows * 28 px * 4 q-threads

typedef float floatx4 __attribute__((ext_vector_type(4)));

// --- pre-pass: per image, sort (box,row-group) tasks by source-y center ---
// Any permutation is correct (it only reorders independent work); the sort
// exists purely so the main kernel's gathers sweep each image top-to-bottom
// (DRAM row-buffer locality instead of random-walk over 256 MB).
__global__ __launch_bounds__(256) void sort_tasks_kernel(
    const float* __restrict__ boxes, int* __restrict__ perm)
{
    const int img = blockIdx.x;
    __shared__ float skey[SORT_N];
    __shared__ int   sval[SORT_N];

    for (int t = threadIdx.x; t < SORT_N; t += 256) {
        float k = 3.0e38f;
        int v = 0;
        if (t < TASKS_PER_IMG) {
            const int box = t / TPB;
            const int rg  = t % TPB;
            const int n   = img * NBOX + box;
            const float y1 = boxes[n * 4 + 0];
            const float y2 = boxes[n * 4 + 2];
            const float hs = (y2 - y1) * (float)(IMG_H - 1) / (float)(CROP - 1);
            k = y1 * (float)(IMG_H - 1) + ((float)(rg * 4) + 1.5f) * hs;
            v = n * TPB + rg;             // global task id
        }
        skey[t] = k;
        sval[t] = v;
    }
    __syncthreads();

    for (int k = 2; k <= SORT_N; k <<= 1) {
        for (int j = k >> 1; j > 0; j >>= 1) {
            for (int t = threadIdx.x; t < SORT_N; t += 256) {
                const int ixj = t ^ j;
                if (ixj > t) {
                    const bool up = ((t & k) == 0);
                    const float a = skey[t], b = skey[ixj];
                    if ((a > b) == up) {
                        skey[t] = b; skey[ixj] = a;
                        const int tv = sval[t];
                        sval[t] = sval[ixj]; sval[ixj] = tv;
                    }
                }
            }
            __syncthreads();
        }
    }

    for (int t = threadIdx.x; t < TASKS_PER_IMG; t += 256)
        perm[img * TASKS_PER_IMG + t] = sval[t];
}

// --- main kernel: identical math to R3, work order permuted by perm ---
template<bool USE_PERM>
__global__ __launch_bounds__(256) void crop_resize_kernel(
    const float* __restrict__ images,
    const float* __restrict__ boxes,
    const int*   __restrict__ perm,
    float* __restrict__ out)
{
    const int tid = blockIdx.x * blockDim.x + threadIdx.x;
    const int total = BATCH * TASKS_PER_IMG * THREADS_PER_TASK;
    if (tid >= total) return;

    const int u = tid / THREADS_PER_TASK;   // sorted slot 0..5599
    const int r = tid % THREADS_PER_TASK;
    const int task = USE_PERM ? perm[u] : u; // n*7 + rg
    const int n  = task / TPB;               // global box 0..799
    const int rg = task % TPB;
    const int rowin = r / 112;               // 0..3
    const int rx = r % 112;
    const int x  = rx >> 2;                  // crop col 0..27
    const int q  = rx & 3;                   // quarter-of-line
    const int y  = rg * 4 + rowin;           // crop row 0..27
    const int b  = n / NBOX;                 // image index

    const float by1 = boxes[n * 4 + 0];
    const float bx1 = boxes[n * 4 + 1];
    const float by2 = boxes[n * 4 + 2];
    const float bx2 = boxes[n * 4 + 3];

    const float Hm1 = (float)(IMG_H - 1);
    const float Wm1 = (float)(IMG_W - 1);
    const float h_scale = (by2 - by1) * Hm1 / (float)(CROP - 1);
    const float w_scale = (bx2 - bx1) * Wm1 / (float)(CROP - 1);

    const float in_y = by1 * Hm1 + (float)y * h_scale;
    const float in_x = bx1 * Wm1 + (float)x * w_scale;

    const bool valid = (in_y >= 0.0f) && (in_y <= Hm1) &&
                       (in_x >= 0.0f) && (in_x <= Wm1);

    const float y0f = floorf(in_y);
    const float x0f = floorf(in_x);
    const float ly = in_y - y0f;
    const float lx = in_x - x0f;

    int y0 = (int)y0f; y0 = y0 < 0 ? 0 : (y0 > IMG_H - 1 ? IMG_H - 1 : y0);
    int x0 = (int)x0f; x0 = x0 < 0 ? 0 : (x0 > IMG_W - 1 ? IMG_W - 1 : x0);
    const int y1i = (y0 + 1 < IMG_H - 1) ? y0 + 1 : IMG_H - 1;
    const int x1i = (x0 + 1 < IMG_W - 1) ? x0 + 1 : IMG_W - 1;

    const int C4 = IMG_C / 4;                 // 8 float4 per pixel
    const floatx4* img4 = (const floatx4*)images;

    const int rowStride = IMG_W * C4;
    const int imgStride = IMG_H * rowStride;
    const int base = b * imgStride;
    const int r0 = base + y0  * rowStride;
    const int r1 = base + y1i * rowStride;

    const int atl = r0 + x0  * C4 + q;
    const int atr = r0 + x1i * C4 + q;
    const int abl = r1 + x0  * C4 + q;
    const int abr = r1 + x1i * C4 + q;

    const floatx4 tl0 = img4[atl];
    const floatx4 tl1 = img4[atl + 4];
    const floatx4 tr0 = img4[atr];
    const floatx4 tr1 = img4[atr + 4];
    const floatx4 bl0 = img4[abl];
    const floatx4 bl1 = img4[abl + 4];
    const floatx4 br0 = img4[abr];
    const floatx4 br1 = img4[abr + 4];

    const floatx4 top0 = tl0 + (tr0 - tl0) * lx;
    const floatx4 bot0 = bl0 + (br0 - bl0) * lx;
    floatx4 res0 = top0 + (bot0 - top0) * ly;

    const floatx4 top1 = tl1 + (tr1 - tl1) * lx;
    const floatx4 bot1 = bl1 + (br1 - bl1) * lx;
    floatx4 res1 = top1 + (bot1 - top1) * ly;

    if (!valid) {
        res0 = (floatx4)0.0f;
        res1 = (floatx4)0.0f;
    }

    const int p = n * (CROP * CROP) + y * CROP + x;
    floatx4* dst = ((floatx4*)out) + p * C4 + q;
    __builtin_nontemporal_store(res0, dst);
    __builtin_nontemporal_store(res1, dst + 4);
}

extern "C" void kernel_launch(void* const* d_in, const int* in_sizes, int n_in,
                              void* d_out, int out_size, void* d_ws, size_t ws_size,
                              hipStream_t stream) {
    const float* images = (const float*)d_in[0];
    const float* boxes  = (const float*)d_in[1];
    float* out = (float*)d_out;
    int* perm = (int*)d_ws;

    const int total = BATCH * TASKS_PER_IMG * THREADS_PER_TASK; // 2,508,800
    const int block = 256;
    const int grid = (total + block - 1) / block;               // 9,800

    const size_t perm_bytes = (size_t)BATCH * TASKS_PER_IMG * sizeof(int);
    if (ws_size >= perm_bytes) {
        sort_tasks_kernel<<<BATCH, 256, 0, stream>>>(boxes, perm);
        crop_resize_kernel<true><<<grid, block, 0, stream>>>(images, boxes, perm, out);
    } else {
        crop_resize_kernel<false><<<grid, block, 0, stream>>>(images, boxes, perm, out);
    }
}

// Round 6
// 52.232 us; speedup vs baseline: 1.6302x; 1.6302x over previous
//
#include <hip/hip_runtime.h>

#define CROP   28
#define NBOX   100
#define IMG_H  512
#define IMG_W  512
#define IMG_C  32
#define BATCH  8

typedef float floatx4 __attribute__((ext_vector_type(4)));

// One thread per (pixel, q) with q in 0..3. Thread q handles float4 groups
// {q, q+4} of the 8 per pixel (byte offsets q*16 and 64+q*16): two dwordx4
// loads per corner (second folds to offset:64), 8 independent gather loads in
// flight per thread. 4 consecutive lanes cover a contiguous 64B per
// instruction; 16 pixels per wave.
//
// R4 lesson: do NOT sort/sweep the gather order — concentrating all CUs on a
// narrow image band serializes onto few HBM channels (52 -> 85 us). Random
// box order maximizes channel parallelism; ~5.1 TB/s effective is the
// scattered-128B-gather ceiling (streaming fill ceiling on this box: ~6.9).
__global__ __launch_bounds__(256) void crop_resize_kernel(
    const float* __restrict__ images,
    const float* __restrict__ boxes,
    float* __restrict__ out)
{
    const int tid = blockIdx.x * blockDim.x + threadIdx.x;
    const int total = BATCH * NBOX * CROP * CROP * 4;
    if (tid >= total) return;

    const int q  = tid & 3;        // quarter-of-line index
    const int p  = tid >> 2;       // pixel id: n*784 + y*28 + x
    const int x  = p % CROP;
    const int t  = p / CROP;
    const int y  = t % CROP;
    const int n  = t / CROP;       // box id 0..799
    const int b  = n / NBOX;       // batch image index

    const float by1 = boxes[n * 4 + 0];
    const float bx1 = boxes[n * 4 + 1];
    const float by2 = boxes[n * 4 + 2];
    const float bx2 = boxes[n * 4 + 3];

    const float Hm1 = (float)(IMG_H - 1);
    const float Wm1 = (float)(IMG_W - 1);
    const float h_scale = (by2 - by1) * Hm1 / (float)(CROP - 1);
    const float w_scale = (bx2 - bx1) * Wm1 / (float)(CROP - 1);

    const float in_y = by1 * Hm1 + (float)y * h_scale;
    const float in_x = bx1 * Wm1 + (float)x * w_scale;

    const bool valid = (in_y >= 0.0f) && (in_y <= Hm1) &&
                       (in_x >= 0.0f) && (in_x <= Wm1);

    const float y0f = floorf(in_y);
    const float x0f = floorf(in_x);
    const float ly = in_y - y0f;
    const float lx = in_x - x0f;

    int y0 = (int)y0f; y0 = y0 < 0 ? 0 : (y0 > IMG_H - 1 ? IMG_H - 1 : y0);
    int x0 = (int)x0f; x0 = x0 < 0 ? 0 : (x0 > IMG_W - 1 ? IMG_W - 1 : x0);
    const int y1i = (y0 + 1 < IMG_H - 1) ? y0 + 1 : IMG_H - 1;
    const int x1i = (x0 + 1 < IMG_W - 1) ? x0 + 1 : IMG_W - 1;

    const int C4 = IMG_C / 4;                 // 8 float4 per pixel
    const floatx4* img4 = (const floatx4*)images;

    const int rowStride = IMG_W * C4;         // float4 units per image row
    const int imgStride = IMG_H * rowStride;  // float4 units per image
    const int base = b * imgStride;
    const int r0 = base + y0  * rowStride;
    const int r1 = base + y1i * rowStride;

    const int atl = r0 + x0  * C4 + q;
    const int atr = r0 + x1i * C4 + q;
    const int abl = r1 + x0  * C4 + q;
    const int abr = r1 + x1i * C4 + q;

    const floatx4 tl0 = img4[atl];
    const floatx4 tl1 = img4[atl + 4];
    const floatx4 tr0 = img4[atr];
    const floatx4 tr1 = img4[atr + 4];
    const floatx4 bl0 = img4[abl];
    const floatx4 bl1 = img4[abl + 4];
    const floatx4 br0 = img4[abr];
    const floatx4 br1 = img4[abr + 4];

    const floatx4 top0 = tl0 + (tr0 - tl0) * lx;
    const floatx4 bot0 = bl0 + (br0 - bl0) * lx;
    floatx4 res0 = top0 + (bot0 - top0) * ly;

    const floatx4 top1 = tl1 + (tr1 - tl1) * lx;
    const floatx4 bot1 = bl1 + (br1 - bl1) * lx;
    floatx4 res1 = top1 + (bot1 - top1) * ly;

    if (!valid) {
        res0 = (floatx4)0.0f;
        res1 = (floatx4)0.0f;
    }

    floatx4* dst = ((floatx4*)out) + p * C4 + q;
    __builtin_nontemporal_store(res0, dst);
    __builtin_nontemporal_store(res1, dst + 4);
}

extern "C" void kernel_launch(void* const* d_in, const int* in_sizes, int n_in,
                              void* d_out, int out_size, void* d_ws, size_t ws_size,
                              hipStream_t stream) {
    const float* images = (const float*)d_in[0];
    const float* boxes  = (const float*)d_in[1];
    float* out = (float*)d_out;

    const int total = BATCH * NBOX * CROP * CROP * 4; // 2,508,800
    const int block = 256;
    const int grid = (total + block - 1) / block;     // 9,800
    crop_resize_kernel<<<grid, block, 0, stream>>>(images, boxes, out);
}